// Round 4
// baseline (133.343 us; speedup 1.0000x reference)
//
#include <hip/hip_runtime.h>
#include <hip/hip_bf16.h>

typedef __attribute__((ext_vector_type(8))) short short8;
typedef __attribute__((ext_vector_type(4))) float floatx4;

#define TINV 14.2857142857142857f               // 1/0.07
#define TL2  20.60992915555662f                  // TINV * log2(e)
#define LN2  0.6931471805599453f
#define SQS  4.539816022451927f                  // sqrt(TL2); dot(fb,fb) = TL2*dot(f,f)
#define NROWS 8192
#define NDIM 128
#define NCH 16
#define NITS 8                                   // 8 x 64 cols = 512-col chunk

__device__ __forceinline__ float fexp2(float x) {
#if __has_builtin(__builtin_amdgcn_exp2f)
    return __builtin_amdgcn_exp2f(x);
#else
    return __expf(x * LN2);
#endif
}

// fp32 -> bf16 with sqrt(TL2) pre-scale; also zero-inits the output scalar
__global__ void convert_kernel(const float* __restrict__ in, unsigned short* __restrict__ out,
                               float* __restrict__ outz) {
    int i = blockIdx.x * 256 + threadIdx.x;
    float4 v = ((const float4*)in)[i];
    union { ushort4 u; __hip_bfloat162 h[2]; } o;
    o.h[0] = __float22bfloat162_rn(float2{v.x * SQS, v.y * SQS});
    o.h[1] = __float22bfloat162_rn(float2{v.z * SQS, v.w * SQS});
    ((ushort4*)out)[i] = o.u;
    if (i == 0) outz[0] = 0.0f;
}

// grid 1024: rb = blockIdx&63 (128 rows), q = blockIdx>>6 (512-col chunk)
// No LDS staging, no in-loop barriers: A and B MFMA fragments loaded directly
// from global bf16 (2 MB, L1/L2-resident). Waves fully independent.
__global__ __launch_bounds__(256) void supcon_main(
    const unsigned short* __restrict__ fb,
    const int* __restrict__ labels,
    float* __restrict__ sM, float* __restrict__ sS, float* __restrict__ sP,
    float* __restrict__ noisep)
{
    __shared__ float nredW[4];

    const int rb = blockIdx.x & 63;
    const int q  = blockIdx.x >> 6;
    const int rowBase = rb << 7;
    const int colBase = q << 9;
    const int tid = threadIdx.x;
    const int w = tid >> 6;
    const int lane = tid & 63;
    const int l15 = lane & 15;
    const int l4  = lane >> 4;

    // A fragments: wave owns 32 rows = 2 rowsets of 16; K=128 register-resident
    short8 afrag[2][4];
    int rw[2], brow[2], lrow[2];
    #pragma unroll
    for (int s = 0; s < 2; ++s) {
        rw[s]   = rowBase + w * 32 + s * 16;
        brow[s] = rw[s] >> 4;
        lrow[s] = labels[brow[s]];
        const short8* src = (const short8*)(fb + (size_t)(rw[s] + l15) * NDIM);
        #pragma unroll
        for (int t = 0; t < 4; ++t) afrag[s][t] = src[t * 4 + l4];
    }

    float tm[2][4], su[2][4], ps[2][4];
    #pragma unroll
    for (int s = 0; s < 2; ++s)
        #pragma unroll
        for (int r = 0; r < 4; ++r) { tm[s][r] = -1e30f; su[s][r] = 0.0f; ps[s][r] = 0.0f; }
    float noise_acc = 0.0f;

    // B fragment base: lane reads 16B at (col)*256B + l4*16B; short8 index = col*16 + l4
    const short8* bbase = (const short8*)fb + (size_t)(colBase + l15) * 16 + l4;

    short8 b0[4], b1[4];
    {   // preload (it=0, c=0)
        const short8* p = bbase;
        b0[0] = p[0]; b0[1] = p[4]; b0[2] = p[8]; b0[3] = p[12];
    }

    floatx4 vacc[2][4];

#define CSTEP(CUR, NXT, c)                                                        \
    {                                                                             \
        const int ni = (it << 2) + (c) + 1;                                       \
        if (ni < 32) {                                                            \
            const short8* p = bbase + ((size_t)(ni >> 2) << 10) + ((ni & 3) << 8);\
            NXT[0] = p[0]; NXT[1] = p[4]; NXT[2] = p[8]; NXT[3] = p[12];          \
        }                                                                         \
        _Pragma("unroll")                                                         \
        for (int s = 0; s < 2; ++s) {                                             \
            floatx4 acc = {0.0f, 0.0f, 0.0f, 0.0f};                               \
            _Pragma("unroll")                                                     \
            for (int t = 0; t < 4; ++t)                                           \
                acc = __builtin_amdgcn_mfma_f32_16x16x32_bf16(afrag[s][t], CUR[t], acc, 0, 0, 0); \
            vacc[s][c] = acc;                                                     \
        }                                                                         \
    }

    for (int it = 0; it < NITS; ++it) {
        CSTEP(b0, b1, 0)
        CSTEP(b1, b0, 1)
        CSTEP(b0, b1, 2)
        CSTEP(b1, b0, 3)

        const int bq0 = (colBase >> 4) + (it << 2);
        const int cl0 = labels[bq0], cl1 = labels[bq0 + 1];
        const int cl2 = labels[bq0 + 2], cl3 = labels[bq0 + 3];
        #pragma unroll
        for (int s = 0; s < 2; ++s) {
            const int nt = brow[s] - bq0;          // same-batch tile index if in [0,4)
            const bool anyn = ((unsigned)nt) < 4u; // wave-uniform
            int posm = 0;
            if (cl0 == lrow[s] && nt != 0) posm |= 1;
            if (cl1 == lrow[s] && nt != 1) posm |= 2;
            if (cl2 == lrow[s] && nt != 2) posm |= 4;
            if (cl3 == lrow[s] && nt != 3) posm |= 8;
            #pragma unroll
            for (int r = 0; r < 4; ++r) {
                const float v0 = vacc[s][0][r], v1 = vacc[s][1][r];
                const float v2 = vacc[s][2][r], v3 = vacc[s][3][r];
                if (!anyn) {
                    const float lmax = fmaxf(fmaxf(v0, v1), fmaxf(v2, v3));
                    const float tmr = tm[s][r];
                    if (__any(lmax > tmr)) {
                        const float tnm = fmaxf(tmr, lmax);
                        const float alpha = fexp2(tmr - tnm);
                        const float e0 = fexp2(v0 - tnm), e1 = fexp2(v1 - tnm);
                        const float e2 = fexp2(v2 - tnm), e3 = fexp2(v3 - tnm);
                        su[s][r] = fmaf(su[s][r], alpha, (e0 + e1) + (e2 + e3));
                        tm[s][r] = tnm;
                    } else {   // common steady-state: max unchanged, no rescale
                        const float e0 = fexp2(v0 - tmr), e1 = fexp2(v1 - tmr);
                        const float e2 = fexp2(v2 - tmr), e3 = fexp2(v3 - tmr);
                        su[s][r] += (e0 + e1) + (e2 + e3);
                    }
                } else {       // rare: one tile is same-batch (invalid + noise pairs)
                    float m3 = -1e30f;
                    if (nt != 0) m3 = fmaxf(m3, v0);
                    if (nt != 1) m3 = fmaxf(m3, v1);
                    if (nt != 2) m3 = fmaxf(m3, v2);
                    if (nt != 3) m3 = fmaxf(m3, v3);
                    const float tmr = tm[s][r];
                    const float tnm = fmaxf(tmr, m3);
                    const float alpha = fexp2(tmr - tnm);
                    float acc4 = 0.0f;
                    if (nt != 0) acc4 += fexp2(v0 - tnm);
                    if (nt != 1) acc4 += fexp2(v1 - tnm);
                    if (nt != 2) acc4 += fexp2(v2 - tnm);
                    if (nt != 3) acc4 += fexp2(v3 - tnm);
                    su[s][r] = fmaf(su[s][r], alpha, acc4);
                    tm[s][r] = tnm;
                    const float vn = (nt == 0) ? v0 : (nt == 1) ? v1 : (nt == 2) ? v2 : v3;
                    const int rl = (l4 << 2) + r;
                    if ((rl >> 3) == (l15 >> 3) && rl != l15) noise_acc += vn;
                }
                if (posm) {
                    if (posm & 1) ps[s][r] += v0;
                    if (posm & 2) ps[s][r] += v1;
                    if (posm & 4) ps[s][r] += v2;
                    if (posm & 8) ps[s][r] += v3;
                }
            }
        }
    }
#undef CSTEP

    // combine the 16 lane-partials per row via shuffles (l15 groups hold one row)
    #pragma unroll
    for (int s = 0; s < 2; ++s)
        #pragma unroll
        for (int r = 0; r < 4; ++r) {
            float tmv = tm[s][r], suv = su[s][r], psv = ps[s][r];
            #pragma unroll
            for (int off = 1; off < 16; off <<= 1) {
                float om = __shfl_xor(tmv, off);
                float os = __shfl_xor(suv, off);
                float op = __shfl_xor(psv, off);
                float nm = fmaxf(tmv, om);
                suv = suv * fexp2(tmv - nm) + os * fexp2(om - nm);
                tmv = nm; psv += op;
            }
            if (l15 == 0) {
                int row = rw[s] + (l4 << 2) + r;
                sM[row * NCH + q] = tmv;
                sS[row * NCH + q] = suv;
                sP[row * NCH + q] = psv;
            }
        }

    float na = noise_acc;
    #pragma unroll
    for (int off = 32; off >= 1; off >>= 1) na += __shfl_xor(na, off);
    if (lane == 0) nredW[w] = na;
    __syncthreads();
    if (tid == 0) noisep[blockIdx.x] = nredW[0] + nredW[1] + nredW[2] + nredW[3];
}

// 32 blocks x 256 threads: per-row chunk merge + class term + noise; atomicAdd to out
__global__ __launch_bounds__(256) void final_k(
    const float* __restrict__ sM, const float* __restrict__ sS, const float* __restrict__ sP,
    const int* __restrict__ labels, const float* __restrict__ noisep,
    float* __restrict__ out)
{
    __shared__ int lab[512];
    __shared__ int hist[16];
    __shared__ float red[256];
    const int tid = threadIdx.x;
    if (tid < 16) hist[tid] = 0;
    lab[tid] = labels[tid];
    lab[tid + 256] = labels[tid + 256];
    __syncthreads();
    atomicAdd(&hist[lab[tid] & 15], 1);
    atomicAdd(&hist[lab[tid + 256] & 15], 1);
    __syncthreads();

    const int row = blockIdx.x * 256 + tid;
    float mq[NCH], sq[NCH], pq[NCH];
    const float4* M4 = (const float4*)(sM + (size_t)row * NCH);
    const float4* S4 = (const float4*)(sS + (size_t)row * NCH);
    const float4* P4 = (const float4*)(sP + (size_t)row * NCH);
    #pragma unroll
    for (int j = 0; j < 4; ++j) {
        float4 a = M4[j]; mq[4*j] = a.x; mq[4*j+1] = a.y; mq[4*j+2] = a.z; mq[4*j+3] = a.w;
        float4 b = S4[j]; sq[4*j] = b.x; sq[4*j+1] = b.y; sq[4*j+2] = b.z; sq[4*j+3] = b.w;
        float4 c = P4[j]; pq[4*j] = c.x; pq[4*j+1] = c.y; pq[4*j+2] = c.z; pq[4*j+3] = c.w;
    }
    float gm = -1e30f;
    #pragma unroll
    for (int qq = 0; qq < NCH; ++qq) gm = fmaxf(gm, mq[qq]);
    float gs = 0.0f, gp = 0.0f;
    #pragma unroll
    for (int qq = 0; qq < NCH; ++qq) { gs += sq[qq] * fexp2(mq[qq] - gm); gp += pq[qq]; }
    const float P = 16.0f * (float)(hist[lab[row >> 4] & 15] - 1);
    // all values are in log2-of-softmax domain (pre-scaled features):
    // L_i = LN2*(gm+log2(gs)); TINV*possum = LN2*gp_scaled
    const float term = LN2 * (P * (gm + __log2f(gs)) - gp) / (P + 1e-8f);

    float contrib = term * (1.0f / (8192.0f * 3.0f));
    if (tid < 32) contrib += noisep[blockIdx.x * 32 + tid] * (-LN2 / (57344.0f * 0.07f * 3.0f));
    red[tid] = contrib;
    __syncthreads();
    #pragma unroll
    for (int off = 128; off > 0; off >>= 1) {
        if (tid < off) red[tid] += red[tid + off];
        __syncthreads();
    }
    if (tid == 0) atomicAdd(out, red[0]);
}

extern "C" void kernel_launch(void* const* d_in, const int* in_sizes, int n_in,
                              void* d_out, int out_size, void* d_ws, size_t ws_size,
                              hipStream_t stream) {
    const float* feat  = (const float*)d_in[0];
    const int* labels  = (const int*)d_in[1];
    float* out = (float*)d_out;

    unsigned short* fb = (unsigned short*)d_ws;                    // 2 MB bf16 (pre-scaled)
    float* wsf    = (float*)((char*)d_ws + (size_t)NROWS * NDIM * 2);
    float* sM     = wsf;                   // 8192*16
    float* sS     = wsf + 131072;
    float* sP     = wsf + 262144;
    float* noisep = wsf + 393216;          // 1024

    hipLaunchKernelGGL(convert_kernel, dim3(1024), dim3(256), 0, stream, feat, fb, out);
    hipLaunchKernelGGL(supcon_main, dim3(1024), dim3(256), 0, stream, fb, labels, sM, sS, sP, noisep);
    hipLaunchKernelGGL(final_k, dim3(32), dim3(256), 0, stream, sM, sS, sP, labels, noisep, out);
}

// Round 5
// 98.227 us; speedup vs baseline: 1.3575x; 1.3575x over previous
//
#include <hip/hip_runtime.h>
#include <hip/hip_bf16.h>

typedef __attribute__((ext_vector_type(8))) short short8;
typedef __attribute__((ext_vector_type(4))) float floatx4;

#define TINV 14.2857142857142857f               // 1/0.07
#define TL2  20.60992915555662f                  // TINV * log2(e)
#define LN2  0.6931471805599453f
#define SQS  4.539816022451927f                  // sqrt(TL2): dot(fb,fb) = TL2*dot(f,f)
#define NROWS 8192
#define NDIM 128
#define NCH 16
#define NITS 16                                  // 16 x 32 cols = 512-col chunk

__device__ __forceinline__ float fexp2(float x) {
#if __has_builtin(__builtin_amdgcn_exp2f)
    return __builtin_amdgcn_exp2f(x);
#else
    return __expf(x * LN2);
#endif
}

// fp32 -> bf16 (pre-scaled by sqrt(TL2)), written TRANSPOSED into fbT:
// fbT 16B-chunk (kc,row) at offset (kc*8192 + row)*16B, kc = k/8. Coalesced writes.
__global__ void convert_kernel(const float* __restrict__ in, unsigned short* __restrict__ fbT,
                               float* __restrict__ outz) {
    const int i = blockIdx.x * 256 + threadIdx.x;   // 512 blocks -> 131072 = 16 kc x 8192 rows
    const int kc = i >> 13;
    const int row = i & 8191;
    const float4* p = (const float4*)(in + (size_t)row * NDIM + kc * 8);
    const float4 a = p[0], b = p[1];
    union { ushort4 u[2]; short8 s; } o;
    o.u[0].x = (unsigned short)(__bfloat16_as_ushort(__float2bfloat16(a.x * SQS)));
    // use packed cvt for all 8:
    union { short8 s; __hip_bfloat162 h[4]; } t;
    t.h[0] = __float22bfloat162_rn(float2{a.x * SQS, a.y * SQS});
    t.h[1] = __float22bfloat162_rn(float2{a.z * SQS, a.w * SQS});
    t.h[2] = __float22bfloat162_rn(float2{b.x * SQS, b.y * SQS});
    t.h[3] = __float22bfloat162_rn(float2{b.z * SQS, b.w * SQS});
    ((short8*)fbT)[(size_t)kc * NROWS + row] = t.s;
    if (i == 0) outz[0] = 0.0f;
}

// grid 1024: rb = blockIdx&63 (128 rows), q = blockIdx>>6 (512-col chunk)
// Double-buffered global_load_lds from fbT (coalesced), K-major LDS, conflict-free ds_read.
__global__ __launch_bounds__(256, 4) void supcon_main(
    const unsigned short* __restrict__ fbT,
    const int* __restrict__ labels,
    float* __restrict__ sM, float* __restrict__ sS, float* __restrict__ sP,
    float* __restrict__ noisep)
{
    __shared__ __align__(16) short stage[2][16 * 32 * 8];   // [buf][kc][col] 16B units, 8KB each
    __shared__ int clab[32];
    __shared__ float nredW[4];

    const int rb = blockIdx.x & 63;
    const int q  = blockIdx.x >> 6;
    const int rowBase = rb << 7;
    const int colBase = q << 9;
    const int tid = threadIdx.x;
    const int w = tid >> 6;
    const int lane = tid & 63;
    const int l15 = lane & 15;
    const int l4  = lane >> 4;
    const int kc_hi = lane >> 5;        // 0/1: which kc within the pair this lane loads
    const int col_l = lane & 31;

    const short8* fb8 = (const short8*)fbT;

// issue staging for tile IT into buffer BUF: 2 instrs/wave, each 1KB = 2 kc-rows x 32 cols
#define ISSUE(IT, BUF)                                                                   \
    {                                                                                    \
        unsigned short* sbase = (unsigned short*)&stage[BUF][0];                         \
        _Pragma("unroll")                                                                \
        for (int j = 0; j < 2; ++j) {                                                    \
            const int kcb = (w << 2) + (j << 1);                                         \
            const unsigned short* src = fbT +                                            \
                ((size_t)(kcb + kc_hi) * NROWS + colBase + ((IT) << 5) + col_l) * 8;     \
            __builtin_amdgcn_global_load_lds(                                            \
                (const __attribute__((address_space(1))) unsigned int*)src,              \
                (__attribute__((address_space(3))) unsigned int*)(sbase + kcb * 256),    \
                16, 0, 0);                                                               \
        }                                                                                \
    }

    ISSUE(0, 0)

    if (tid < 32) clab[tid] = labels[(colBase >> 4) + tid];

    // A fragments: wave owns 32 rows = 2 rowsets of 16; from fbT (coalesced 256B segs)
    short8 afrag[2][4];
    int rw[2], brow[2], lrow[2];
    #pragma unroll
    for (int s = 0; s < 2; ++s) {
        rw[s]   = rowBase + w * 32 + s * 16;
        brow[s] = rw[s] >> 4;
        lrow[s] = labels[brow[s]];
        #pragma unroll
        for (int t = 0; t < 4; ++t)
            afrag[s][t] = fb8[(size_t)(t * 4 + l4) * NROWS + rw[s] + l15];
    }

    float tm[2][4], su[2][4], ps[2][4];
    #pragma unroll
    for (int s = 0; s < 2; ++s)
        #pragma unroll
        for (int r = 0; r < 4; ++r) { tm[s][r] = -1e30f; su[s][r] = 0.0f; ps[s][r] = 0.0f; }
    float noise_acc = 0.0f;

    __syncthreads();

    for (int it = 0; it < NITS; ++it) {
        if (it + 1 < NITS) ISSUE(it + 1, (it + 1) & 1)

        const short8* stv = (const short8*)stage[it & 1];
        floatx4 vacc[2][2];
        #pragma unroll
        for (int c = 0; c < 2; ++c) {
            short8 bfrag[4];
            #pragma unroll
            for (int t = 0; t < 4; ++t)
                bfrag[t] = stv[(t * 4 + l4) * 32 + c * 16 + l15];   // 2-way bank = free
            #pragma unroll
            for (int s = 0; s < 2; ++s) {
                floatx4 acc = {0.0f, 0.0f, 0.0f, 0.0f};
                #pragma unroll
                for (int t = 0; t < 4; ++t)
                    acc = __builtin_amdgcn_mfma_f32_16x16x32_bf16(afrag[s][t], bfrag[t], acc, 0, 0, 0);
                vacc[s][c] = acc;
            }
        }

        const int base16 = (colBase >> 4) + (it << 1);
        const int cl0 = clab[(it << 1)], cl1 = clab[(it << 1) + 1];
        #pragma unroll
        for (int s = 0; s < 2; ++s) {
            const int nt = brow[s] - base16;       // same-batch tile index if in [0,2)
            const bool anyn = ((unsigned)nt) < 2u; // wave-uniform
            int posm = 0;
            if (cl0 == lrow[s] && nt != 0) posm |= 1;
            if (cl1 == lrow[s] && nt != 1) posm |= 2;
            #pragma unroll
            for (int r = 0; r < 4; ++r) {
                const float v0 = vacc[s][0][r], v1 = vacc[s][1][r];
                if (!anyn) {
                    const float lmax = fmaxf(v0, v1);
                    const float tmr = tm[s][r];
                    if (__any(lmax > tmr)) {
                        const float tnm = fmaxf(tmr, lmax);
                        su[s][r] = fmaf(su[s][r], fexp2(tmr - tnm),
                                        fexp2(v0 - tnm) + fexp2(v1 - tnm));
                        tm[s][r] = tnm;
                    } else {   // steady state: no rescale
                        su[s][r] += fexp2(v0 - tmr) + fexp2(v1 - tmr);
                    }
                } else {       // one of the two 16-tiles is same-batch (invalid + noise)
                    const float vv = nt ? v0 : v1;   // the valid tile's value
                    const float vn = nt ? v1 : v0;   // the same-batch tile's value
                    const float tmr = tm[s][r];
                    const float tnm = fmaxf(tmr, vv);
                    su[s][r] = fmaf(su[s][r], fexp2(tmr - tnm), fexp2(vv - tnm));
                    tm[s][r] = tnm;
                    const int rl = (l4 << 2) + r;
                    if ((rl >> 3) == (l15 >> 3) && rl != l15) noise_acc += vn;
                }
                if (posm & 1) ps[s][r] += v0;
                if (posm & 2) ps[s][r] += v1;
            }
        }
        __syncthreads();
    }
#undef ISSUE

    // combine the 16 lane-partials per row via shuffles (l15 groups hold one row)
    #pragma unroll
    for (int s = 0; s < 2; ++s)
        #pragma unroll
        for (int r = 0; r < 4; ++r) {
            float tmv = tm[s][r], suv = su[s][r], psv = ps[s][r];
            #pragma unroll
            for (int off = 1; off < 16; off <<= 1) {
                float om = __shfl_xor(tmv, off);
                float os = __shfl_xor(suv, off);
                float op = __shfl_xor(psv, off);
                float nm = fmaxf(tmv, om);
                suv = suv * fexp2(tmv - nm) + os * fexp2(om - nm);
                tmv = nm; psv += op;
            }
            if (l15 == 0) {
                int row = rw[s] + (l4 << 2) + r;
                sM[row * NCH + q] = tmv;
                sS[row * NCH + q] = suv;
                sP[row * NCH + q] = psv;
            }
        }

    float na = noise_acc;
    #pragma unroll
    for (int off = 32; off >= 1; off >>= 1) na += __shfl_xor(na, off);
    if (lane == 0) nredW[w] = na;
    __syncthreads();
    if (tid == 0) noisep[blockIdx.x] = nredW[0] + nredW[1] + nredW[2] + nredW[3];
}

// 32 blocks x 256 threads: per-row chunk merge + class term + noise; atomicAdd to out
__global__ __launch_bounds__(256) void final_k(
    const float* __restrict__ sM, const float* __restrict__ sS, const float* __restrict__ sP,
    const int* __restrict__ labels, const float* __restrict__ noisep,
    float* __restrict__ out)
{
    __shared__ int lab[512];
    __shared__ int hist[16];
    __shared__ float red[256];
    const int tid = threadIdx.x;
    if (tid < 16) hist[tid] = 0;
    lab[tid] = labels[tid];
    lab[tid + 256] = labels[tid + 256];
    __syncthreads();
    atomicAdd(&hist[lab[tid] & 15], 1);
    atomicAdd(&hist[lab[tid + 256] & 15], 1);
    __syncthreads();

    const int row = blockIdx.x * 256 + tid;
    float mq[NCH], sq[NCH], pq[NCH];
    const float4* M4 = (const float4*)(sM + (size_t)row * NCH);
    const float4* S4 = (const float4*)(sS + (size_t)row * NCH);
    const float4* P4 = (const float4*)(sP + (size_t)row * NCH);
    #pragma unroll
    for (int j = 0; j < 4; ++j) {
        float4 a = M4[j]; mq[4*j] = a.x; mq[4*j+1] = a.y; mq[4*j+2] = a.z; mq[4*j+3] = a.w;
        float4 b = S4[j]; sq[4*j] = b.x; sq[4*j+1] = b.y; sq[4*j+2] = b.z; sq[4*j+3] = b.w;
        float4 c = P4[j]; pq[4*j] = c.x; pq[4*j+1] = c.y; pq[4*j+2] = c.z; pq[4*j+3] = c.w;
    }
    float gm = -1e30f;
    #pragma unroll
    for (int qq = 0; qq < NCH; ++qq) gm = fmaxf(gm, mq[qq]);
    float gs = 0.0f, gp = 0.0f;
    #pragma unroll
    for (int qq = 0; qq < NCH; ++qq) { gs += sq[qq] * fexp2(mq[qq] - gm); gp += pq[qq]; }
    const float P = 16.0f * (float)(hist[lab[row >> 4] & 15] - 1);
    // log2-domain (pre-scaled features): term = LN2*(P*(gm+log2 gs) - possum)/(P+eps)
    const float term = LN2 * (P * (gm + __log2f(gs)) - gp) / (P + 1e-8f);

    float contrib = term * (1.0f / (8192.0f * 3.0f));
    if (tid < 32) contrib += noisep[blockIdx.x * 32 + tid] * (-LN2 / (57344.0f * 0.07f * 3.0f));
    red[tid] = contrib;
    __syncthreads();
    #pragma unroll
    for (int off = 128; off > 0; off >>= 1) {
        if (tid < off) red[tid] += red[tid + off];
        __syncthreads();
    }
    if (tid == 0) atomicAdd(out, red[0]);
}

extern "C" void kernel_launch(void* const* d_in, const int* in_sizes, int n_in,
                              void* d_out, int out_size, void* d_ws, size_t ws_size,
                              hipStream_t stream) {
    const float* feat  = (const float*)d_in[0];
    const int* labels  = (const int*)d_in[1];
    float* out = (float*)d_out;

    unsigned short* fbT = (unsigned short*)d_ws;                   // 2 MB bf16 transposed
    float* wsf    = (float*)((char*)d_ws + (size_t)NROWS * NDIM * 2);
    float* sM     = wsf;                   // 8192*16
    float* sS     = wsf + 131072;
    float* sP     = wsf + 262144;
    float* noisep = wsf + 393216;          // 1024

    hipLaunchKernelGGL(convert_kernel, dim3(512), dim3(256), 0, stream, feat, fbT, out);
    hipLaunchKernelGGL(supcon_main, dim3(1024), dim3(256), 0, stream, fbT, labels, sM, sS, sP, noisep);
    hipLaunchKernelGGL(final_k, dim3(32), dim3(256), 0, stream, sM, sS, sP, labels, noisep, out);
}